// Round 5
// baseline (33.068 us; speedup 1.0000x reference)
//
#include <hip/hip_runtime.h>

#define H 128
#define W 128
#define C 64
#define HW (H * W)
#define RAD 2
#define KD 5
#define KK 25

#define TSX 16
#define TSY 16
#define HROWS 20          // halo rows  (y0-2 .. y0+17)
#define HCOLS 24          // halo cols  (x0-4 .. x0+19), 16B-aligned staging
#define RSTR 24           // LDS row stride (floats)
#define PSTR 484          // plane stride: 20*24=480 +4 (keeps 16B align)
#define GS   (8 * PSTR + 8) // cs-group stride: +8 floats staggers bank phase
#define CB 32             // channels staged per round
#define ROUNDS 2
#define LDSF (4 * GS)     // 15520 floats = 60.6 KB -> 2 blocks/CU

// cs-group reduction on the VALU pipe (gfx950 permlane swaps), no LDS traffic.
__device__ __forceinline__ float cs_reduce(float x)
{
    float a = x, b = x;
    asm("v_permlane16_swap_b32 %0, %1" : "+v"(a), "+v"(b));
    float s = a + b;
    float c = s, d = s;
    asm("v_permlane32_swap_b32 %0, %1" : "+v"(c), "+v"(d));
    return c + d;
}

__device__ __forceinline__ float2 softmax_eo(float (&cr)[KK], int xx, int yy)
{
    const float scale = 0.125f; // 1/sqrt(64)
    float m = -1e30f;
#pragma unroll
    for (int ky = 0; ky < KD; ++ky) {
        int syy = yy + ky - RAD;
#pragma unroll
        for (int kx = 0; kx < KD; ++kx) {
            int sxx = xx + kx - RAD;
            int k = ky * KD + kx;
            float cv = cr[k] * scale;
            bool valid = (sxx >= 0) && (sxx < W) && (syy >= 0) && (syy < H);
            cv = valid ? cv : -1e9f;
            cr[k] = cv;
            m = fmaxf(m, cv);
        }
    }
    float sum = 0.f, ox = 0.f, oy = 0.f;
#pragma unroll
    for (int ky = 0; ky < KD; ++ky)
#pragma unroll
        for (int kx = 0; kx < KD; ++kx) {
            int k = ky * KD + kx;
            float e = __expf(cr[k] - m);
            sum += e;
            ox += e * (float)(kx - RAD);
            oy += e * (float)(ky - RAD);
        }
    float inv = 1.f / sum;
    return make_float2(ox * inv, oy * inv);
}

__global__ __launch_bounds__(256, 2)
void bam_corr_softmax_kernel(const float* __restrict__ f0,
                             const float* __restrict__ f1,
                             const float* __restrict__ f2,
                             float* __restrict__ out)
{
    __shared__ float lds[LDSF];

    const int tid  = threadIdx.x;
    const int lane = tid & 63;
    const int wav  = tid >> 6;
    const int cs   = lane >> 4;        // channel group 0..3 (16 ch each)
    const int s    = lane & 15;
    const int qx   = s & 7;            // quad x 0..7
    const int qy   = wav * 2 + (s >> 3); // quad y 0..7
    const int lx   = qx * 2;           // local x of quad (even)
    const int ly   = qy * 2;           // local y of quad (even)

    // XCD banding: band = tileY = blockIdx.x % 8 -> one XCD L2 holds the
    // 16-row band working set (~3.1 MB). Consecutive blocks on an XCD cycle
    // the 8 (v,b) jobs of the same tile.
    const int i     = blockIdx.x;
    const int band  = i & 7;           // tileY
    const int j     = i >> 3;
    const int img   = j & 7;           // v*2 + b
    const int tileX = j >> 3;          // 0..7

    const int v = img >> 1;
    const int b = img & 1;

    const float* A;
    const float* Bf;
    if (v == 0)      { A = f0; Bf = f2; }
    else if (v == 1) { A = f1; Bf = f2; }
    else if (v == 2) { A = f2; Bf = f0; }
    else             { A = f2; Bf = f1; }

    const int x0 = tileX * TSX;
    const int y0 = band * TSY;
    const int x  = x0 + lx;
    const int y  = y0 + ly;

    const float* Arow  = A + (size_t)b * C * HW + (size_t)y * W + x;
    const float* Bbase = Bf + (size_t)b * C * HW;

    float c00[KK], c01[KK], c10[KK], c11[KK];
#pragma unroll
    for (int k = 0; k < KK; ++k) { c00[k]=0.f; c01[k]=0.f; c10[k]=0.f; c11[k]=0.f; }

    for (int rnd = 0; rnd < ROUNDS; ++rnd) {
        // ---- stage CB channel planes (20x24 halo) as aligned float4 ----
        // 32 planes * 20 rows * 6 chunks = 3840 = 15 per thread exactly
        for (int q = tid; q < CB * HROWS * 6; q += 256) {
            int p   = q / (HROWS * 6);
            int rem = q - p * (HROWS * 6);
            int row = rem / 6;
            int c6  = rem - row * 6;
            int ch  = rnd * CB + p;
            int gy  = y0 - 2 + row;
            int gx  = x0 - 4 + c6 * 4;
            float4 val;
            if (gy >= 0 && gy < H && gx >= 0 && gx + 3 < W) {
                val = *reinterpret_cast<const float4*>(
                    Bbase + (size_t)ch * HW + (size_t)(gy * W + gx));
            } else {
                float vv[4];
#pragma unroll
                for (int e = 0; e < 4; ++e) {
                    int gxe = gx + e;
                    vv[e] = (gy >= 0 && gy < H && gxe >= 0 && gxe < W)
                          ? Bbase[(size_t)ch * HW + (size_t)(gy * W + gxe)]
                          : 0.f;
                }
                val = make_float4(vv[0], vv[1], vv[2], vv[3]);
            }
            int g = p >> 3, c = p & 7;
            *reinterpret_cast<float4*>(&lds[g * GS + c * PSTR + row * RSTR + c6 * 4]) = val;
        }
        __syncthreads();

        // ---- compute: 8 channels per cs-group, 2x2 outputs per thread ----
#pragma unroll
        for (int c = 0; c < 8; ++c) {
            const int ch = rnd * CB + cs * 8 + c;
            float2 aT = *reinterpret_cast<const float2*>(Arow + (size_t)ch * HW);
            float2 aB = *reinterpret_cast<const float2*>(Arow + (size_t)ch * HW + W);
            // storage col (lx+2) == global col x-2 (window start), 8B aligned
            const float* bp = &lds[cs * GS + c * PSTR + ly * RSTR + lx + 2];
#pragma unroll
            for (int rr = 0; rr < 6; ++rr) {
                const float* rp = bp + rr * RSTR;
                float2 w01 = *reinterpret_cast<const float2*>(rp);
                float2 w23 = *reinterpret_cast<const float2*>(rp + 2);
                float2 w45 = *reinterpret_cast<const float2*>(rp + 4);
                float w[6] = { w01.x, w01.y, w23.x, w23.y, w45.x, w45.y };
                if (rr < 5) {
#pragma unroll
                    for (int kx = 0; kx < KD; ++kx) {
                        c00[rr*KD+kx] = fmaf(aT.x, w[kx],   c00[rr*KD+kx]);
                        c01[rr*KD+kx] = fmaf(aT.y, w[kx+1], c01[rr*KD+kx]);
                    }
                }
                if (rr >= 1) {
#pragma unroll
                    for (int kx = 0; kx < KD; ++kx) {
                        c10[(rr-1)*KD+kx] = fmaf(aB.x, w[kx],   c10[(rr-1)*KD+kx]);
                        c11[(rr-1)*KD+kx] = fmaf(aB.y, w[kx+1], c11[(rr-1)*KD+kx]);
                    }
                }
            }
        }
        __syncthreads();
    }

    // ---- reduce the 4 channel-group partials (VALU permlane swaps) ----
#pragma unroll
    for (int k = 0; k < KK; ++k) {
        c00[k] = cs_reduce(c00[k]);
        c01[k] = cs_reduce(c01[k]);
        c10[k] = cs_reduce(c10[k]);
        c11[k] = cs_reduce(c11[k]);
    }

    // ---- masked softmax + expected offset for the 2x2 quad ----
    float2 r00 = softmax_eo(c00, x,     y);
    float2 r01 = softmax_eo(c01, x + 1, y);
    float2 r10 = softmax_eo(c10, x,     y + 1);
    float2 r11 = softmax_eo(c11, x + 1, y + 1);

    if (cs == 0) {
        size_t ob = ((size_t)img * 2) * HW + (size_t)y * W + x;
        *reinterpret_cast<float2*>(&out[ob])          = make_float2(r00.x, r01.x);
        *reinterpret_cast<float2*>(&out[ob + W])      = make_float2(r10.x, r11.x);
        *reinterpret_cast<float2*>(&out[ob + HW])     = make_float2(r00.y, r01.y);
        *reinterpret_cast<float2*>(&out[ob + HW + W]) = make_float2(r10.y, r11.y);
    }
}

extern "C" void kernel_launch(void* const* d_in, const int* in_sizes, int n_in,
                              void* d_out, int out_size, void* d_ws, size_t ws_size,
                              hipStream_t stream)
{
    const float* f0 = (const float*)d_in[0];
    const float* f1 = (const float*)d_in[1];
    const float* f2 = (const float*)d_in[2];
    float* out = (float*)d_out;

    dim3 block(256, 1, 1);
    dim3 grid(512, 1, 1); // 8 bands x 8 img x 8 tileX, tiles of 16x16
    bam_corr_softmax_kernel<<<grid, block, 0, stream>>>(f0, f1, f2, out);
}

// Round 6
// 26.185 us; speedup vs baseline: 1.2628x; 1.2628x over previous
//
#include <hip/hip_runtime.h>

#define H 128
#define W 128
#define C 64
#define HW (H * W)
#define RAD 2
#define KD 5
#define KK 25

#define TSX 16
#define TSY 8
#define HROWS 12          // halo rows (y0-2 .. y0+9)
#define RSTR 24           // u32 (channel-pairs) per halo row (x0-4 .. x0+19)
#define PSTR 292          // u32 per pair-plane: 12*24=288 +4 pad (16B-aligned)
#define NPAIR 32          // 64 channels as 32 pairs, all staged at once
#define LDSU (NPAIR * PSTR) // 9344 u32 = 36.5 KB -> 4 blocks/CU

typedef _Float16 h2 __attribute__((ext_vector_type(2)));

__device__ __forceinline__ float dot2acc(h2 a, h2 w, float acc)
{
#if __has_builtin(__builtin_amdgcn_fdot2)
    return __builtin_amdgcn_fdot2(a, w, acc, false);   // v_dot2_f32_f16
#else
    return fmaf((float)a.x, (float)w.x, fmaf((float)a.y, (float)w.y, acc));
#endif
}

__device__ __forceinline__ uint32_t pkh2(float lo, float hi)
{
    h2 t; t.x = (_Float16)lo; t.y = (_Float16)hi;     // RTE converts + pack
    return __builtin_bit_cast(uint32_t, t);
}

__device__ __forceinline__ h2 bch2(uint32_t u) { return __builtin_bit_cast(h2, u); }

// cs-group reduction on the VALU pipe (gfx950 permlane swaps), no LDS traffic.
__device__ __forceinline__ float cs_reduce(float x)
{
    float a = x, b = x;
    asm("v_permlane16_swap_b32 %0, %1" : "+v"(a), "+v"(b));
    float s = a + b;
    float c = s, d = s;
    asm("v_permlane32_swap_b32 %0, %1" : "+v"(c), "+v"(d));
    return c + d;
}

__device__ __forceinline__ float2 softmax_eo(float (&cr)[KK], int xx, int yy)
{
    const float scale = 0.125f; // 1/sqrt(64)
    float m = -1e30f;
#pragma unroll
    for (int ky = 0; ky < KD; ++ky) {
        int syy = yy + ky - RAD;
#pragma unroll
        for (int kx = 0; kx < KD; ++kx) {
            int sxx = xx + kx - RAD;
            int k = ky * KD + kx;
            float cv = cr[k] * scale;
            bool valid = (sxx >= 0) && (sxx < W) && (syy >= 0) && (syy < H);
            cv = valid ? cv : -1e9f;
            cr[k] = cv;
            m = fmaxf(m, cv);
        }
    }
    float sum = 0.f, ox = 0.f, oy = 0.f;
#pragma unroll
    for (int ky = 0; ky < KD; ++ky)
#pragma unroll
        for (int kx = 0; kx < KD; ++kx) {
            int k = ky * KD + kx;
            float e = __expf(cr[k] - m);
            sum += e;
            ox += e * (float)(kx - RAD);
            oy += e * (float)(ky - RAD);
        }
    float inv = 1.f / sum;
    return make_float2(ox * inv, oy * inv);
}

__global__ __launch_bounds__(256, 4)
void bam_corr_softmax_kernel(const float* __restrict__ f0,
                             const float* __restrict__ f1,
                             const float* __restrict__ f2,
                             float* __restrict__ out)
{
    __shared__ uint32_t lds[LDSU];

    const int tid  = threadIdx.x;
    const int lane = tid & 63;
    const int wav  = tid >> 6;
    const int cs   = lane >> 4;        // channel group 0..3 (8 pairs each)
    const int s    = lane & 15;
    const int sy   = s >> 2;           // 0..3
    const int sxp  = s & 3;            // 0..3
    const int wx   = wav & 1;
    const int wy   = wav >> 1;
    const int lx   = wx * 8 + sxp * 2; // local x of first output (even)
    const int ly   = wy * 4 + sy;      // local y

    // XCD banding: band = blockIdx.x % 8 -> 16-row y-band per XCD L2 (~3.1MB).
    const int i     = blockIdx.x;
    const int band  = i & 7;
    const int j     = i >> 3;
    const int img   = j & 7;           // v*2 + b
    const int t     = j >> 3;          // 0..15
    const int tileX = t & 7;           // 0..7
    const int tileY = band * 2 + (t >> 3); // 0..15

    const int v = img >> 1;
    const int b = img & 1;

    const float* A;
    const float* Bf;
    if (v == 0)      { A = f0; Bf = f2; }
    else if (v == 1) { A = f1; Bf = f2; }
    else if (v == 2) { A = f2; Bf = f0; }
    else             { A = f2; Bf = f1; }

    const int x0 = tileX * TSX;
    const int y0 = tileY * TSY;
    const int x  = x0 + lx;
    const int y  = y0 + ly;

    const float* Arow  = A + (size_t)b * C * HW + (size_t)(y * W + x);
    const float* Bbase = Bf + (size_t)b * C * HW;

    // ---- stage ALL 64 channels as 32 f16 pair-planes (20x24 halo) ----
    // 32 planes * 12 rows * 6 chunks = 2304 = 9 per thread exactly
    const bool interior = (tileX >= 1) && (tileX <= 6) && (tileY >= 1) && (tileY <= 14);
#pragma unroll
    for (int it = 0; it < 9; ++it) {
        int q   = tid + it * 256;
        int p   = q / 72;              // pair-plane 0..31
        int rem = q - p * 72;
        int row = rem / 6;
        int c6  = rem - row * 6;
        int gy  = y0 - 2 + row;
        int gx  = x0 - 4 + c6 * 4;
        float4 lo, hi;
        if (interior) {
            const float* p0 = Bbase + (size_t)(2 * p) * HW + (size_t)(gy * W + gx);
            lo = *reinterpret_cast<const float4*>(p0);
            hi = *reinterpret_cast<const float4*>(p0 + HW);
        } else {
            float lv[4], hv[4];
#pragma unroll
            for (int e = 0; e < 4; ++e) {
                int gxe = gx + e;
                bool ok = (gy >= 0) && (gy < H) && (gxe >= 0) && (gxe < W);
                size_t off = (size_t)(2 * p) * HW + (size_t)(ok ? gy * W + gxe : 0);
                lv[e] = ok ? Bbase[off] : 0.f;
                hv[e] = ok ? Bbase[off + HW] : 0.f;
            }
            lo = make_float4(lv[0], lv[1], lv[2], lv[3]);
            hi = make_float4(hv[0], hv[1], hv[2], hv[3]);
        }
        uint4 wq = make_uint4(pkh2(lo.x, hi.x), pkh2(lo.y, hi.y),
                              pkh2(lo.z, hi.z), pkh2(lo.w, hi.w));
        *reinterpret_cast<uint4*>(&lds[p * PSTR + row * RSTR + c6 * 4]) = wq;
    }
    __syncthreads();   // the ONLY barrier

    // ---- compute: 8 channel-pairs per cs-group, 2 x-outputs per thread ----
    float c0[KK], c1[KK];
#pragma unroll
    for (int k = 0; k < KK; ++k) { c0[k] = 0.f; c1[k] = 0.f; }

#pragma unroll
    for (int c = 0; c < 8; ++c) {
        const int pl = cs * 8 + c;
        const float* ap = Arow + (size_t)(2 * pl) * HW;
        float2 alo = *reinterpret_cast<const float2*>(ap);       // ch 2pl   @ x,x+1
        float2 ahi = *reinterpret_cast<const float2*>(ap + HW);  // ch 2pl+1 @ x,x+1
        h2 a0, a1;
        a0.x = (_Float16)alo.x; a0.y = (_Float16)ahi.x;
        a1.x = (_Float16)alo.y; a1.y = (_Float16)ahi.y;
        // storage col (lx+2) == global col x-2 (window start), 8B aligned
        const uint32_t* bp = &lds[pl * PSTR + ly * RSTR + lx + 2];
#pragma unroll
        for (int rr = 0; rr < KD; ++rr) {
            const uint32_t* rp = bp + rr * RSTR;
            uint2 u01 = *reinterpret_cast<const uint2*>(rp);
            uint2 u23 = *reinterpret_cast<const uint2*>(rp + 2);
            uint2 u45 = *reinterpret_cast<const uint2*>(rp + 4);
            h2 w0 = bch2(u01.x), w1 = bch2(u01.y), w2 = bch2(u23.x);
            h2 w3 = bch2(u23.y), w4 = bch2(u45.x), w5 = bch2(u45.y);
            const int kb = rr * KD;
            c0[kb + 0] = dot2acc(a0, w0, c0[kb + 0]);
            c0[kb + 1] = dot2acc(a0, w1, c0[kb + 1]);
            c0[kb + 2] = dot2acc(a0, w2, c0[kb + 2]);
            c0[kb + 3] = dot2acc(a0, w3, c0[kb + 3]);
            c0[kb + 4] = dot2acc(a0, w4, c0[kb + 4]);
            c1[kb + 0] = dot2acc(a1, w1, c1[kb + 0]);
            c1[kb + 1] = dot2acc(a1, w2, c1[kb + 1]);
            c1[kb + 2] = dot2acc(a1, w3, c1[kb + 2]);
            c1[kb + 3] = dot2acc(a1, w4, c1[kb + 3]);
            c1[kb + 4] = dot2acc(a1, w5, c1[kb + 4]);
        }
    }

    // ---- reduce the 4 channel-group partials (VALU permlane swaps) ----
#pragma unroll
    for (int k = 0; k < KK; ++k) {
        c0[k] = cs_reduce(c0[k]);
        c1[k] = cs_reduce(c1[k]);
    }

    // ---- masked softmax + expected offset for both outputs ----
    float2 r0 = softmax_eo(c0, x,     y);
    float2 r1 = softmax_eo(c1, x + 1, y);

    if (cs == 0) {
        size_t ob = ((size_t)img * 2) * HW + (size_t)(y * W + x);
        *reinterpret_cast<float2*>(&out[ob])      = make_float2(r0.x, r1.x);
        *reinterpret_cast<float2*>(&out[ob + HW]) = make_float2(r0.y, r1.y);
    }
}

extern "C" void kernel_launch(void* const* d_in, const int* in_sizes, int n_in,
                              void* d_out, int out_size, void* d_ws, size_t ws_size,
                              hipStream_t stream)
{
    const float* f0 = (const float*)d_in[0];
    const float* f1 = (const float*)d_in[1];
    const float* f2 = (const float*)d_in[2];
    float* out = (float*)d_out;

    dim3 block(256, 1, 1);
    dim3 grid(1024, 1, 1); // 8 bands x 8 img x 16 tiles of 16x8
    bam_corr_softmax_kernel<<<grid, block, 0, stream>>>(f0, f1, f2, out);
}